// Round 2
// baseline (592.800 us; speedup 1.0000x reference)
//
#include <hip/hip_runtime.h>
#include <hip/hip_bf16.h>

#define N_BUS   2000
#define BATCH   512
#define NNODES  (BATCH * N_BUS)      // 1,024,000
#define NEDGES  3072000

constexpr float SN_INV     = 0.01f;                 // 1/SN_MVA
constexpr float ALPHA_C    = 0.9f;
constexpr float PHYS_SCALE = 0.02f;
constexpr float DEG2RAD_C  = 0.017453292519943295f;

// ---------------- reduction helper ----------------
__device__ __forceinline__ float wave_reduce(float v) {
    #pragma unroll
    for (int off = 32; off > 0; off >>= 1) v += __shfl_down(v, off, 64);
    return v;
}

// ---------------- kernel 1: node prep + mse partials ----------------
// x_phys[node] = {vm, va_deg, p_pu, q_pu}; acc[0] += sum((yp-yt)^2)
__global__ __launch_bounds__(256) void node_prep(
    const float* __restrict__ y_pred, const float* __restrict__ y_true,
    const float* __restrict__ x_input,
    const float* __restrict__ x_mean, const float* __restrict__ x_std,
    const float* __restrict__ y_mean, const float* __restrict__ y_std,
    float* __restrict__ x_phys, float* __restrict__ acc)
{
    int node = blockIdx.x * blockDim.x + threadIdx.x;
    float msep = 0.0f;
    if (node < NNODES) {
        int i = node % N_BUS;
        float ys0 = y_std[i*2],  ys1 = y_std[i*2+1];
        float ym0 = y_mean[i*2], ym1 = y_mean[i*2+1];
        float2 pr = *reinterpret_cast<const float2*>(y_pred + (size_t)node*2);
        float2 tr = *reinterpret_cast<const float2*>(y_true + (size_t)node*2);
        float yp0 = pr.x*ys0 + ym0, yp1 = pr.y*ys1 + ym1;
        float yt0 = tr.x*ys0 + ym0, yt1 = tr.y*ys1 + ym1;
        float d0 = yp0 - yt0, d1 = yp1 - yt1;
        msep = d0*d0 + d1*d1;
        // x_input row: stride 7, need cols 0,1 (node*28B not 8B-aligned -> scalar loads)
        float xi0 = x_input[(size_t)node*7 + 0];
        float xi1 = x_input[(size_t)node*7 + 1];
        float p = (xi0 * x_std[i*7 + 0] + x_mean[i*7 + 0]) * SN_INV;
        float q = (xi1 * x_std[i*7 + 1] + x_mean[i*7 + 1]) * SN_INV;
        float4 xp = make_float4(yp0, yp1, p, q);
        *reinterpret_cast<float4*>(x_phys + (size_t)node*4) = xp;
    }
    // block reduce -> one atomic
    __shared__ float red[4];
    float v = wave_reduce(msep);
    int lane = threadIdx.x & 63, wid = threadIdx.x >> 6;
    if (lane == 0) red[wid] = v;
    __syncthreads();
    if (threadIdx.x == 0) {
        float s = red[0] + red[1] + red[2] + red[3];
        unsafeAtomicAdd(acc + 0, s);
    }
}

// ---------------- kernel 2: per-edge message + scatter-add by src ----------------
__global__ __launch_bounds__(256) void edge_kernel(
    const int* __restrict__ eidx, const float* __restrict__ eattr,
    const float* __restrict__ e_mean, const float* __restrict__ e_std,
    const float* __restrict__ x_phys, float* __restrict__ agg)
{
    int e = blockIdx.x * blockDim.x + threadIdx.x;
    if (e >= NEDGES) return;
    int s = eidx[e];
    int d = eidx[NEDGES + e];
    float4 ea = *reinterpret_cast<const float4*>(eattr + (size_t)e*4);
    float Gs = ea.x * e_std[0] + e_mean[0];
    float Bs = ea.y * e_std[1] + e_mean[1];
    float Gm = ea.z * e_std[2] + e_mean[2];
    float Bm = ea.w * e_std[3] + e_mean[3];
    float4 xi = *reinterpret_cast<const float4*>(x_phys + (size_t)s*4);
    float4 xj = *reinterpret_cast<const float4*>(x_phys + (size_t)d*4);
    float vai = xi.y * DEG2RAD_C, vaj = xj.y * DEG2RAD_C;
    float si, ci, sj, cj;
    sincosf(vai, &si, &ci);
    sincosf(vaj, &sj, &cj);
    float e_i = xi.x * ci, f_i = xi.x * si;
    float e_j = xj.x * cj, f_j = xj.x * sj;
    float I_re = Gs*e_i - Bs*f_i + Gm*e_j - Bm*f_j;
    float I_im = Gs*f_i + Bs*e_i + Gm*f_j + Bm*e_j;
    float Pji = -(e_i*I_re + f_i*I_im);
    float Qji = -(f_i*I_re - e_i*I_im);
    unsafeAtomicAdd(agg + (size_t)s*2 + 0, Pji);
    unsafeAtomicAdd(agg + (size_t)s*2 + 1, Qji);
}

// ---------------- kernel 3: per-node imbalance + weighted partials ----------------
// acc[1] += sum(sq*w), acc[2] += sum(w)
__global__ __launch_bounds__(256) void node_final(
    const float* __restrict__ x_phys, const float* __restrict__ agg,
    const int* __restrict__ mask, const float* __restrict__ shunt,
    float* __restrict__ acc)
{
    int node = blockIdx.x * blockDim.x + threadIdx.x;
    float sqw = 0.0f, w = 0.0f;
    if (node < NNODES) {
        int i = node % N_BUS;
        float4 xp = *reinterpret_cast<const float4*>(x_phys + (size_t)node*4);
        float2 ag = *reinterpret_cast<const float2*>(agg + (size_t)node*2);
        float vm2 = xp.x * xp.x;
        float dP = -ag.x + xp.z + vm2 * shunt[i*2 + 0];
        float dQ = -ag.y + xp.w - vm2 * shunt[i*2 + 1];
        w = (mask[i] != 0) ? 1.0f : 0.0f;
        sqw = (dP*dP + dQ*dQ) * w;
    }
    __shared__ float red0[4], red1[4];
    float v0 = wave_reduce(sqw);
    float v1 = wave_reduce(w);
    int lane = threadIdx.x & 63, wid = threadIdx.x >> 6;
    if (lane == 0) { red0[wid] = v0; red1[wid] = v1; }
    __syncthreads();
    if (threadIdx.x == 0) {
        unsafeAtomicAdd(acc + 1, red0[0] + red0[1] + red0[2] + red0[3]);
        unsafeAtomicAdd(acc + 2, red1[0] + red1[1] + red1[2] + red1[3]);
    }
}

// ---------------- kernel 4: combine ----------------
__global__ void finalize_kernel(const float* __restrict__ acc, float* __restrict__ out) {
    if (threadIdx.x == 0 && blockIdx.x == 0) {
        float mse  = acc[0] / (float)(NNODES * 2);
        float phys = acc[1] / acc[2];
        out[0] = ALPHA_C * mse + (1.0f - ALPHA_C) * PHYS_SCALE * phys;
    }
}

extern "C" void kernel_launch(void* const* d_in, const int* in_sizes, int n_in,
                              void* d_out, int out_size, void* d_ws, size_t ws_size,
                              hipStream_t stream) {
    const float* y_pred    = (const float*)d_in[0];
    const float* y_true    = (const float*)d_in[1];
    const float* x_input   = (const float*)d_in[2];
    const int*   edge_idx  = (const int*)  d_in[3];
    const float* edge_attr = (const float*)d_in[4];
    const float* x_mean    = (const float*)d_in[5];
    const float* x_std     = (const float*)d_in[6];
    const float* y_mean    = (const float*)d_in[7];
    const float* y_std     = (const float*)d_in[8];
    const float* edge_mean = (const float*)d_in[9];
    const float* edge_std  = (const float*)d_in[10];
    const int*   load_mask = (const int*)  d_in[11];   // bool in ref; assuming int32 0/1 per harness contract
    const float* shunt     = (const float*)d_in[12];

    float* x_phys = (float*)d_ws;                       // NNODES*4 floats
    float* agg    = x_phys + (size_t)NNODES * 4;        // NNODES*2 floats
    float* acc    = agg    + (size_t)NNODES * 2;        // 3 floats (+pad)

    // zero agg + accumulators (graph-capture-safe)
    hipMemsetAsync(agg, 0, ((size_t)NNODES * 2 + 16) * sizeof(float), stream);

    dim3 blk(256);
    node_prep<<<dim3(NNODES / 256), blk, 0, stream>>>(
        y_pred, y_true, x_input, x_mean, x_std, y_mean, y_std, x_phys, acc);
    edge_kernel<<<dim3(NEDGES / 256), blk, 0, stream>>>(
        edge_idx, edge_attr, edge_mean, edge_std, x_phys, agg);
    node_final<<<dim3(NNODES / 256), blk, 0, stream>>>(
        x_phys, agg, load_mask, shunt, acc);
    finalize_kernel<<<1, 64, 0, stream>>>(acc, (float*)d_out);
}

// Round 3
// 589.144 us; speedup vs baseline: 1.0062x; 1.0062x over previous
//
#include <hip/hip_runtime.h>
#include <hip/hip_bf16.h>
#include <hip/hip_fp16.h>

#define N_BUS   2000
#define BATCH   512
#define NNODES  (BATCH * N_BUS)      // 1,024,000
#define NEDGES  3072000

constexpr float SN_INV     = 0.01f;                 // 1/SN_MVA
constexpr float ALPHA_C    = 0.9f;
constexpr float PHYS_SCALE = 0.02f;
constexpr float DEG2RAD_C  = 0.017453292519943295f;

typedef float v2f __attribute__((ext_vector_type(2)));

// packed v2f32 atomic add (gfx90a+/CDNA3/4: global_atomic_pk_add_f32)
__device__ __forceinline__ void atomic_pk_add(float* addr, float a, float b) {
#if __has_builtin(__builtin_amdgcn_global_atomic_fadd_v2f32)
    v2f v; v.x = a; v.y = b;
    __builtin_amdgcn_global_atomic_fadd_v2f32(
        (__attribute__((address_space(1))) v2f*)(void*)addr, v);
#else
    unsafeAtomicAdd(addr + 0, a);
    unsafeAtomicAdd(addr + 1, b);
#endif
}

__device__ __forceinline__ float wave_reduce(float v) {
    #pragma unroll
    for (int off = 32; off > 0; off >>= 1) v += __shfl_down(v, off, 64);
    return v;
}

// ---------------- kernel 1: node prep ----------------
// ef[node]   = half2(vm*cos(va_rad), vm*sin(va_rad))      (4 MB -> L2-resident gather array)
// base[node] = float2(p + vm^2*shP, q - vm^2*shQ)
// agg[node]  = 0
// acc[0]    += sum((yp-yt)^2)
__global__ __launch_bounds__(256) void node_prep(
    const float* __restrict__ y_pred, const float* __restrict__ y_true,
    const float* __restrict__ x_input,
    const float* __restrict__ x_mean, const float* __restrict__ x_std,
    const float* __restrict__ y_mean, const float* __restrict__ y_std,
    const float* __restrict__ shunt,
    __half2* __restrict__ ef, float2* __restrict__ base,
    float2* __restrict__ agg, float* __restrict__ acc)
{
    int node = blockIdx.x * blockDim.x + threadIdx.x;
    int i = node % N_BUS;
    float2 ys = *reinterpret_cast<const float2*>(y_std  + (size_t)i*2);
    float2 ym = *reinterpret_cast<const float2*>(y_mean + (size_t)i*2);
    float2 pr = *reinterpret_cast<const float2*>(y_pred + (size_t)node*2);
    float2 tr = *reinterpret_cast<const float2*>(y_true + (size_t)node*2);
    float yp0 = fmaf(pr.x, ys.x, ym.x), yp1 = fmaf(pr.y, ys.y, ym.y);
    float yt0 = fmaf(tr.x, ys.x, ym.x), yt1 = fmaf(tr.y, ys.y, ym.y);
    float d0 = yp0 - yt0, d1 = yp1 - yt1;
    float msep = d0*d0 + d1*d1;

    // e,f from vm=yp0, va=yp1
    float s, c;
    sincosf(yp1 * DEG2RAD_C, &s, &c);
    ef[node] = __floats2half2_rn(yp0 * c, yp0 * s);

    // p,q + shunt folded into per-node base
    float xi0 = x_input[(size_t)node*7 + 0];
    float xi1 = x_input[(size_t)node*7 + 1];
    float p = fmaf(xi0, x_std[i*7 + 0], x_mean[i*7 + 0]) * SN_INV;
    float q = fmaf(xi1, x_std[i*7 + 1], x_mean[i*7 + 1]) * SN_INV;
    float vm2 = yp0 * yp0;
    float2 sh = *reinterpret_cast<const float2*>(shunt + (size_t)i*2);
    base[node] = make_float2(fmaf(vm2, sh.x, p), fmaf(-vm2, sh.y, q));
    agg[node]  = make_float2(0.0f, 0.0f);

    __shared__ float red[4];
    float v = wave_reduce(msep);
    int lane = threadIdx.x & 63, wid = threadIdx.x >> 6;
    if (lane == 0) red[wid] = v;
    __syncthreads();
    if (threadIdx.x == 0)
        unsafeAtomicAdd(acc + 0, red[0] + red[1] + red[2] + red[3]);
}

// ---------------- kernel 2: per-edge message + packed scatter-add ----------------
__global__ __launch_bounds__(256) void edge_kernel(
    const int* __restrict__ eidx, const float* __restrict__ eattr,
    const float* __restrict__ e_mean, const float* __restrict__ e_std,
    const __half2* __restrict__ ef, float2* __restrict__ agg)
{
    int e = blockIdx.x * blockDim.x + threadIdx.x;
    int s = eidx[e];
    int d = eidx[NEDGES + e];
    float4 ea = *reinterpret_cast<const float4*>(eattr + (size_t)e*4);
    float Gs = fmaf(ea.x, e_std[0], e_mean[0]);
    float Bs = fmaf(ea.y, e_std[1], e_mean[1]);
    float Gm = fmaf(ea.z, e_std[2], e_mean[2]);
    float Bm = fmaf(ea.w, e_std[3], e_mean[3]);
    float2 fi = __half22float2(ef[s]);   // (e_i, f_i)
    float2 fj = __half22float2(ef[d]);   // (e_j, f_j)
    float e_i = fi.x, f_i = fi.y;
    float e_j = fj.x, f_j = fj.y;
    float I_re = Gs*e_i - Bs*f_i + Gm*e_j - Bm*f_j;
    float I_im = Gs*f_i + Bs*e_i + Gm*f_j + Bm*e_j;
    float Pji = -(e_i*I_re + f_i*I_im);
    float Qji = -(f_i*I_re - e_i*I_im);
    atomic_pk_add(reinterpret_cast<float*>(agg + s), Pji, Qji);
}

// ---------------- kernel 3: per-node imbalance + weighted partials ----------------
__global__ __launch_bounds__(256) void node_final(
    const float2* __restrict__ base, const float2* __restrict__ agg,
    const int* __restrict__ mask, float* __restrict__ acc)
{
    int node = blockIdx.x * blockDim.x + threadIdx.x;
    int i = node % N_BUS;
    float2 bs = base[node];
    float2 ag = agg[node];
    float dP = bs.x - ag.x;
    float dQ = bs.y - ag.y;
    float w  = (mask[i] != 0) ? 1.0f : 0.0f;
    float sqw = (dP*dP + dQ*dQ) * w;

    __shared__ float red0[4], red1[4];
    float v0 = wave_reduce(sqw);
    float v1 = wave_reduce(w);
    int lane = threadIdx.x & 63, wid = threadIdx.x >> 6;
    if (lane == 0) { red0[wid] = v0; red1[wid] = v1; }
    __syncthreads();
    if (threadIdx.x == 0) {
        unsafeAtomicAdd(acc + 1, red0[0] + red0[1] + red0[2] + red0[3]);
        unsafeAtomicAdd(acc + 2, red1[0] + red1[1] + red1[2] + red1[3]);
    }
}

// ---------------- kernel 4: combine ----------------
__global__ void finalize_kernel(const float* __restrict__ acc, float* __restrict__ out) {
    if (threadIdx.x == 0 && blockIdx.x == 0) {
        float mse  = acc[0] / (float)(NNODES * 2);
        float phys = acc[1] / acc[2];
        out[0] = ALPHA_C * mse + (1.0f - ALPHA_C) * PHYS_SCALE * phys;
    }
}

extern "C" void kernel_launch(void* const* d_in, const int* in_sizes, int n_in,
                              void* d_out, int out_size, void* d_ws, size_t ws_size,
                              hipStream_t stream) {
    const float* y_pred    = (const float*)d_in[0];
    const float* y_true    = (const float*)d_in[1];
    const float* x_input   = (const float*)d_in[2];
    const int*   edge_idx  = (const int*)  d_in[3];
    const float* edge_attr = (const float*)d_in[4];
    const float* x_mean    = (const float*)d_in[5];
    const float* x_std     = (const float*)d_in[6];
    const float* y_mean    = (const float*)d_in[7];
    const float* y_std     = (const float*)d_in[8];
    const float* edge_mean = (const float*)d_in[9];
    const float* edge_std  = (const float*)d_in[10];
    const int*   load_mask = (const int*)  d_in[11];
    const float* shunt     = (const float*)d_in[12];

    // ws layout (all 8B-aligned): agg float2[N] | base float2[N] | ef half2[N] | acc
    float2*  agg  = (float2*)d_ws;
    float2*  base = agg + NNODES;
    __half2* ef   = (__half2*)(base + NNODES);
    float*   acc  = (float*)(ef + NNODES);

    hipMemsetAsync(acc, 0, 16, stream);   // zero the 3 scalar accumulators

    dim3 blk(256);
    node_prep<<<dim3(NNODES / 256), blk, 0, stream>>>(
        y_pred, y_true, x_input, x_mean, x_std, y_mean, y_std, shunt,
        ef, base, agg, acc);
    edge_kernel<<<dim3(NEDGES / 256), blk, 0, stream>>>(
        edge_idx, edge_attr, edge_mean, edge_std, ef, agg);
    node_final<<<dim3(NNODES / 256), blk, 0, stream>>>(
        base, agg, load_mask, acc);
    finalize_kernel<<<1, 64, 0, stream>>>(acc, (float*)d_out);
}

// Round 7
// 443.839 us; speedup vs baseline: 1.3356x; 1.3274x over previous
//
#include <hip/hip_runtime.h>
#include <hip/hip_bf16.h>
#include <hip/hip_fp16.h>

#define N_BUS   2000
#define BATCH   512
#define NNODES  (BATCH * N_BUS)      // 1,024,000
#define NEDGES  3072000

constexpr float SN_INV     = 0.01f;                 // 1/SN_MVA
constexpr float ALPHA_C    = 0.9f;
constexpr float PHYS_SCALE = 0.02f;
constexpr float DEG2RAD_C  = 0.017453292519943295f;

typedef float v4f __attribute__((ext_vector_type(4)));   // nontemporal-load-compatible

// one-dword packed f16 atomic: (P,Q) in a single 32B-sector transaction
__device__ __forceinline__ void atomic_pk_add_h2(__half2* addr, float P, float Q) {
    __half2 v = __floats2half2_rn(P, Q);
#if __has_builtin(__builtin_amdgcn_global_atomic_fadd_v2f16)
    typedef _Float16 v2h __attribute__((ext_vector_type(2)));
    __builtin_amdgcn_global_atomic_fadd_v2f16(
        (__attribute__((address_space(1))) v2h*)(void*)addr,
        *reinterpret_cast<v2h*>(&v));
#else
    unsafeAtomicAdd(addr, v);   // HIP __half2 overload (pk_add_f16)
#endif
}

__device__ __forceinline__ float wave_reduce(float v) {
    #pragma unroll
    for (int off = 32; off > 0; off >>= 1) v += __shfl_down(v, off, 64);
    return v;
}

// ---------------- kernel 1: node prep ----------------
// ef[node]   = half2(vm*cos, vm*sin)   (4 MB gather array, L2-resident)
// base[node] = float2(p + vm^2*shP, q - vm^2*shQ)
// agg[node]  = half2(0,0)
// acc[0]    += sum((yp-yt)^2)
__global__ __launch_bounds__(256) void node_prep(
    const float* __restrict__ y_pred, const float* __restrict__ y_true,
    const float* __restrict__ x_input,
    const float* __restrict__ x_mean, const float* __restrict__ x_std,
    const float* __restrict__ y_mean, const float* __restrict__ y_std,
    const float* __restrict__ shunt,
    __half2* __restrict__ ef, float2* __restrict__ base,
    __half2* __restrict__ agg, float* __restrict__ acc)
{
    int node = blockIdx.x * blockDim.x + threadIdx.x;
    int i = node % N_BUS;
    float2 ys = *reinterpret_cast<const float2*>(y_std  + (size_t)i*2);
    float2 ym = *reinterpret_cast<const float2*>(y_mean + (size_t)i*2);
    float2 pr = *reinterpret_cast<const float2*>(y_pred + (size_t)node*2);
    float2 tr = *reinterpret_cast<const float2*>(y_true + (size_t)node*2);
    float yp0 = fmaf(pr.x, ys.x, ym.x), yp1 = fmaf(pr.y, ys.y, ym.y);
    float yt0 = fmaf(tr.x, ys.x, ym.x), yt1 = fmaf(tr.y, ys.y, ym.y);
    float d0 = yp0 - yt0, d1 = yp1 - yt1;
    float msep = d0*d0 + d1*d1;

    float s, c;
    __sincosf(yp1 * DEG2RAD_C, &s, &c);   // |angle| < ~0.2 rad; HW approx fine
    ef[node] = __floats2half2_rn(yp0 * c, yp0 * s);

    float xi0 = x_input[(size_t)node*7 + 0];
    float xi1 = x_input[(size_t)node*7 + 1];
    float p = fmaf(xi0, x_std[i*7 + 0], x_mean[i*7 + 0]) * SN_INV;
    float q = fmaf(xi1, x_std[i*7 + 1], x_mean[i*7 + 1]) * SN_INV;
    float vm2 = yp0 * yp0;
    float2 sh = *reinterpret_cast<const float2*>(shunt + (size_t)i*2);
    base[node] = make_float2(fmaf(vm2, sh.x, p), fmaf(-vm2, sh.y, q));
    agg[node]  = __floats2half2_rn(0.0f, 0.0f);

    __shared__ float red[4];
    float v = wave_reduce(msep);
    int lane = threadIdx.x & 63, wid = threadIdx.x >> 6;
    if (lane == 0) red[wid] = v;
    __syncthreads();
    if (threadIdx.x == 0)
        unsafeAtomicAdd(acc + 0, red[0] + red[1] + red[2] + red[3]);
}

// ---------------- kernel 2: per-edge message + single-dword scatter-add ----------------
__global__ __launch_bounds__(256) void edge_kernel(
    const int* __restrict__ eidx, const float* __restrict__ eattr,
    const float* __restrict__ e_mean, const float* __restrict__ e_std,
    const __half2* __restrict__ ef, __half2* __restrict__ agg)
{
    int e = blockIdx.x * blockDim.x + threadIdx.x;
    int s = __builtin_nontemporal_load(eidx + e);
    int d = __builtin_nontemporal_load(eidx + NEDGES + e);
    const v4f* eav = reinterpret_cast<const v4f*>(eattr) + e;
    v4f ea = __builtin_nontemporal_load(eav);
    float Gs = fmaf(ea.x, e_std[0], e_mean[0]);
    float Bs = fmaf(ea.y, e_std[1], e_mean[1]);
    float Gm = fmaf(ea.z, e_std[2], e_mean[2]);
    float Bm = fmaf(ea.w, e_std[3], e_mean[3]);
    float2 fi = __half22float2(ef[s]);   // (e_i, f_i)
    float2 fj = __half22float2(ef[d]);   // (e_j, f_j)
    float e_i = fi.x, f_i = fi.y;
    float e_j = fj.x, f_j = fj.y;
    float I_re = Gs*e_i - Bs*f_i + Gm*e_j - Bm*f_j;
    float I_im = Gs*f_i + Bs*e_i + Gm*f_j + Bm*e_j;
    float Pji = -(e_i*I_re + f_i*I_im);
    float Qji = -(f_i*I_re - e_i*I_im);
    atomic_pk_add_h2(agg + s, Pji, Qji);
}

// ---------------- kernel 3: per-node imbalance + weighted partials ----------------
__global__ __launch_bounds__(256) void node_final(
    const float2* __restrict__ base, const __half2* __restrict__ agg,
    const int* __restrict__ mask, float* __restrict__ acc)
{
    int node = blockIdx.x * blockDim.x + threadIdx.x;
    int i = node % N_BUS;
    float2 bs = base[node];
    float2 ag = __half22float2(agg[node]);
    float dP = bs.x - ag.x;
    float dQ = bs.y - ag.y;
    float w  = (mask[i] != 0) ? 1.0f : 0.0f;
    float sqw = (dP*dP + dQ*dQ) * w;

    __shared__ float red0[4], red1[4];
    float v0 = wave_reduce(sqw);
    float v1 = wave_reduce(w);
    int lane = threadIdx.x & 63, wid = threadIdx.x >> 6;
    if (lane == 0) { red0[wid] = v0; red1[wid] = v1; }
    __syncthreads();
    if (threadIdx.x == 0) {
        unsafeAtomicAdd(acc + 1, red0[0] + red0[1] + red0[2] + red0[3]);
        unsafeAtomicAdd(acc + 2, red1[0] + red1[1] + red1[2] + red1[3]);
    }
}

// ---------------- kernel 4: combine ----------------
__global__ void finalize_kernel(const float* __restrict__ acc, float* __restrict__ out) {
    if (threadIdx.x == 0 && blockIdx.x == 0) {
        float mse  = acc[0] / (float)(NNODES * 2);
        float phys = acc[1] / acc[2];
        out[0] = ALPHA_C * mse + (1.0f - ALPHA_C) * PHYS_SCALE * phys;
    }
}

extern "C" void kernel_launch(void* const* d_in, const int* in_sizes, int n_in,
                              void* d_out, int out_size, void* d_ws, size_t ws_size,
                              hipStream_t stream) {
    const float* y_pred    = (const float*)d_in[0];
    const float* y_true    = (const float*)d_in[1];
    const float* x_input   = (const float*)d_in[2];
    const int*   edge_idx  = (const int*)  d_in[3];
    const float* edge_attr = (const float*)d_in[4];
    const float* x_mean    = (const float*)d_in[5];
    const float* x_std     = (const float*)d_in[6];
    const float* y_mean    = (const float*)d_in[7];
    const float* y_std     = (const float*)d_in[8];
    const float* edge_mean = (const float*)d_in[9];
    const float* edge_std  = (const float*)d_in[10];
    const int*   load_mask = (const int*)  d_in[11];
    const float* shunt     = (const float*)d_in[12];

    // ws layout: base float2[N] | agg half2[N] | ef half2[N] | acc
    float2*  base = (float2*)d_ws;
    __half2* agg  = (__half2*)(base + NNODES);
    __half2* ef   = agg + NNODES;
    float*   acc  = (float*)(ef + NNODES);

    (void)hipMemsetAsync(acc, 0, 16, stream);

    dim3 blk(256);
    node_prep<<<dim3(NNODES / 256), blk, 0, stream>>>(
        y_pred, y_true, x_input, x_mean, x_std, y_mean, y_std, shunt,
        ef, base, agg, acc);
    edge_kernel<<<dim3(NEDGES / 256), blk, 0, stream>>>(
        edge_idx, edge_attr, edge_mean, edge_std, ef, agg);
    node_final<<<dim3(NNODES / 256), blk, 0, stream>>>(
        base, agg, load_mask, acc);
    finalize_kernel<<<1, 64, 0, stream>>>(acc, (float*)d_out);
}

// Round 8
// 368.763 us; speedup vs baseline: 1.6075x; 1.2036x over previous
//
#include <hip/hip_runtime.h>
#include <hip/hip_bf16.h>
#include <hip/hip_fp16.h>

#define N_BUS   2000
#define BATCH   512
#define NNODES  (BATCH * N_BUS)      // 1,024,000
#define NEDGES  3072000

constexpr float SN_INV     = 0.01f;                 // 1/SN_MVA
constexpr float ALPHA_C    = 0.9f;
constexpr float PHYS_SCALE = 0.02f;
constexpr float DEG2RAD_C  = 0.017453292519943295f;

typedef float v4f __attribute__((ext_vector_type(4)));   // nontemporal-load-compatible

// one-dword packed f16 atomic: (P,Q) in a single 32B-sector transaction
__device__ __forceinline__ void atomic_pk_add_h2(__half2* addr, float P, float Q) {
    __half2 v = __floats2half2_rn(P, Q);
#if __has_builtin(__builtin_amdgcn_global_atomic_fadd_v2f16)
    typedef _Float16 v2h __attribute__((ext_vector_type(2)));
    __builtin_amdgcn_global_atomic_fadd_v2f16(
        (__attribute__((address_space(1))) v2h*)(void*)addr,
        *reinterpret_cast<v2h*>(&v));
#else
    unsafeAtomicAdd(addr, v);   // HIP __half2 overload (pk_add_f16)
#endif
}

__device__ __forceinline__ float wave_reduce(float v) {
    #pragma unroll
    for (int off = 32; off > 0; off >>= 1) v += __shfl_down(v, off, 64);
    return v;
}

// ---------------- kernel 1: node prep (2 nodes/thread) ----------------
__global__ __launch_bounds__(256) void node_prep(
    const float* __restrict__ y_pred, const float* __restrict__ y_true,
    const float* __restrict__ x_input,
    const float* __restrict__ x_mean, const float* __restrict__ x_std,
    const float* __restrict__ y_mean, const float* __restrict__ y_std,
    const float* __restrict__ shunt,
    __half2* __restrict__ ef, float2* __restrict__ base,
    __half2* __restrict__ agg, float* __restrict__ acc)
{
    int t = blockIdx.x * blockDim.x + threadIdx.x;   // handles nodes 2t, 2t+1
    int n0 = t * 2;
    int i0 = n0 % N_BUS;
    int i1 = (i0 + 1 == N_BUS) ? 0 : i0 + 1;

    float4 pr = *reinterpret_cast<const float4*>(y_pred + (size_t)n0*2);
    float4 tr = *reinterpret_cast<const float4*>(y_true + (size_t)n0*2);
    float2 ysA = *reinterpret_cast<const float2*>(y_std  + (size_t)i0*2);
    float2 ymA = *reinterpret_cast<const float2*>(y_mean + (size_t)i0*2);
    float2 ysB = *reinterpret_cast<const float2*>(y_std  + (size_t)i1*2);
    float2 ymB = *reinterpret_cast<const float2*>(y_mean + (size_t)i1*2);

    float ypA0 = fmaf(pr.x, ysA.x, ymA.x), ypA1 = fmaf(pr.y, ysA.y, ymA.y);
    float ytA0 = fmaf(tr.x, ysA.x, ymA.x), ytA1 = fmaf(tr.y, ysA.y, ymA.y);
    float ypB0 = fmaf(pr.z, ysB.x, ymB.x), ypB1 = fmaf(pr.w, ysB.y, ymB.y);
    float ytB0 = fmaf(tr.z, ysB.x, ymB.x), ytB1 = fmaf(tr.w, ysB.y, ymB.y);
    float dA0 = ypA0 - ytA0, dA1 = ypA1 - ytA1;
    float dB0 = ypB0 - ytB0, dB1 = ypB1 - ytB1;
    float msep = dA0*dA0 + dA1*dA1 + dB0*dB0 + dB1*dB1;

    float sA, cA, sB, cB;
    __sincosf(ypA1 * DEG2RAD_C, &sA, &cA);
    __sincosf(ypB1 * DEG2RAD_C, &sB, &cB);
    __half2 efA = __floats2half2_rn(ypA0 * cA, ypA0 * sA);
    __half2 efB = __floats2half2_rn(ypB0 * cB, ypB0 * sB);
    *reinterpret_cast<uint2*>(ef + n0) =
        make_uint2(*reinterpret_cast<unsigned*>(&efA), *reinterpret_cast<unsigned*>(&efB));

    float xiA0 = x_input[(size_t)n0*7 + 0];
    float xiA1 = x_input[(size_t)n0*7 + 1];
    float xiB0 = x_input[(size_t)n0*7 + 7];
    float xiB1 = x_input[(size_t)n0*7 + 8];
    float pA = fmaf(xiA0, x_std[i0*7 + 0], x_mean[i0*7 + 0]) * SN_INV;
    float qA = fmaf(xiA1, x_std[i0*7 + 1], x_mean[i0*7 + 1]) * SN_INV;
    float pB = fmaf(xiB0, x_std[i1*7 + 0], x_mean[i1*7 + 0]) * SN_INV;
    float qB = fmaf(xiB1, x_std[i1*7 + 1], x_mean[i1*7 + 1]) * SN_INV;
    float vmA2 = ypA0 * ypA0, vmB2 = ypB0 * ypB0;
    float2 shA = *reinterpret_cast<const float2*>(shunt + (size_t)i0*2);
    float2 shB = *reinterpret_cast<const float2*>(shunt + (size_t)i1*2);
    float4 bs;
    bs.x = fmaf(vmA2, shA.x, pA); bs.y = fmaf(-vmA2, shA.y, qA);
    bs.z = fmaf(vmB2, shB.x, pB); bs.w = fmaf(-vmB2, shB.y, qB);
    *reinterpret_cast<float4*>(base + n0) = bs;
    *reinterpret_cast<uint2*>(agg + n0) = make_uint2(0u, 0u);

    __shared__ float red[4];
    float v = wave_reduce(msep);
    int lane = threadIdx.x & 63, wid = threadIdx.x >> 6;
    if (lane == 0) red[wid] = v;
    __syncthreads();
    if (threadIdx.x == 0)
        unsafeAtomicAdd(acc + 0, red[0] + red[1] + red[2] + red[3]);
}

// ---------------- kernel 2: per-edge message + single-dword scatter-add ----------------
// At the measured atomic wall: 3.07M tx / 19.7 G tx/s = 156 us. Do not expect byte
// optimizations to move this; only tx-count reductions would (none exist for random keys).
__global__ __launch_bounds__(256) void edge_kernel(
    const int* __restrict__ eidx, const float* __restrict__ eattr,
    const float* __restrict__ e_mean, const float* __restrict__ e_std,
    const __half2* __restrict__ ef, __half2* __restrict__ agg)
{
    int e = blockIdx.x * blockDim.x + threadIdx.x;
    int s = __builtin_nontemporal_load(eidx + e);
    int d = __builtin_nontemporal_load(eidx + NEDGES + e);
    const v4f* eav = reinterpret_cast<const v4f*>(eattr) + e;
    v4f ea = __builtin_nontemporal_load(eav);
    float Gs = fmaf(ea.x, e_std[0], e_mean[0]);
    float Bs = fmaf(ea.y, e_std[1], e_mean[1]);
    float Gm = fmaf(ea.z, e_std[2], e_mean[2]);
    float Bm = fmaf(ea.w, e_std[3], e_mean[3]);
    float2 fi = __half22float2(ef[s]);   // (e_i, f_i)
    float2 fj = __half22float2(ef[d]);   // (e_j, f_j)
    float e_i = fi.x, f_i = fi.y;
    float e_j = fj.x, f_j = fj.y;
    float I_re = Gs*e_i - Bs*f_i + Gm*e_j - Bm*f_j;
    float I_im = Gs*f_i + Bs*e_i + Gm*f_j + Bm*e_j;
    float Pji = -(e_i*I_re + f_i*I_im);
    float Qji = -(f_i*I_re - e_i*I_im);
    atomic_pk_add_h2(agg + s, Pji, Qji);
}

// ---------------- kernel 3: per-node imbalance (2 nodes/thread) ----------------
__global__ __launch_bounds__(256) void node_final(
    const float2* __restrict__ base, const __half2* __restrict__ agg,
    const int* __restrict__ mask, float* __restrict__ acc)
{
    int t = blockIdx.x * blockDim.x + threadIdx.x;
    int n0 = t * 2;
    int i0 = n0 % N_BUS;
    int i1 = (i0 + 1 == N_BUS) ? 0 : i0 + 1;
    float4 bs = *reinterpret_cast<const float4*>(base + n0);
    uint2 agu = *reinterpret_cast<const uint2*>(agg + n0);
    float2 agA = __half22float2(*reinterpret_cast<__half2*>(&agu.x));
    float2 agB = __half22float2(*reinterpret_cast<__half2*>(&agu.y));
    float dPA = bs.x - agA.x, dQA = bs.y - agA.y;
    float dPB = bs.z - agB.x, dQB = bs.w - agB.y;
    float wA = (mask[i0] != 0) ? 1.0f : 0.0f;
    float wB = (mask[i1] != 0) ? 1.0f : 0.0f;
    float sqw = (dPA*dPA + dQA*dQA) * wA + (dPB*dPB + dQB*dQB) * wB;
    float w = wA + wB;

    __shared__ float red0[4], red1[4];
    float v0 = wave_reduce(sqw);
    float v1 = wave_reduce(w);
    int lane = threadIdx.x & 63, wid = threadIdx.x >> 6;
    if (lane == 0) { red0[wid] = v0; red1[wid] = v1; }
    __syncthreads();
    if (threadIdx.x == 0) {
        unsafeAtomicAdd(acc + 1, red0[0] + red0[1] + red0[2] + red0[3]);
        unsafeAtomicAdd(acc + 2, red1[0] + red1[1] + red1[2] + red1[3]);
    }
}

// ---------------- kernel 4: combine ----------------
__global__ void finalize_kernel(const float* __restrict__ acc, float* __restrict__ out) {
    if (threadIdx.x == 0 && blockIdx.x == 0) {
        float mse  = acc[0] / (float)(NNODES * 2);
        float phys = acc[1] / acc[2];
        out[0] = ALPHA_C * mse + (1.0f - ALPHA_C) * PHYS_SCALE * phys;
    }
}

extern "C" void kernel_launch(void* const* d_in, const int* in_sizes, int n_in,
                              void* d_out, int out_size, void* d_ws, size_t ws_size,
                              hipStream_t stream) {
    const float* y_pred    = (const float*)d_in[0];
    const float* y_true    = (const float*)d_in[1];
    const float* x_input   = (const float*)d_in[2];
    const int*   edge_idx  = (const int*)  d_in[3];
    const float* edge_attr = (const float*)d_in[4];
    const float* x_mean    = (const float*)d_in[5];
    const float* x_std     = (const float*)d_in[6];
    const float* y_mean    = (const float*)d_in[7];
    const float* y_std     = (const float*)d_in[8];
    const float* edge_mean = (const float*)d_in[9];
    const float* edge_std  = (const float*)d_in[10];
    const int*   load_mask = (const int*)  d_in[11];
    const float* shunt     = (const float*)d_in[12];

    // ws layout: base float2[N] | agg half2[N] | ef half2[N] | acc
    float2*  base = (float2*)d_ws;
    __half2* agg  = (__half2*)(base + NNODES);
    __half2* ef   = agg + NNODES;
    float*   acc  = (float*)(ef + NNODES);

    (void)hipMemsetAsync(acc, 0, 16, stream);

    dim3 blk(256);
    node_prep<<<dim3(NNODES / 512), blk, 0, stream>>>(
        y_pred, y_true, x_input, x_mean, x_std, y_mean, y_std, shunt,
        ef, base, agg, acc);
    edge_kernel<<<dim3(NEDGES / 256), blk, 0, stream>>>(
        edge_idx, edge_attr, edge_mean, edge_std, ef, agg);
    node_final<<<dim3(NNODES / 512), blk, 0, stream>>>(
        base, agg, load_mask, acc);
    finalize_kernel<<<1, 64, 0, stream>>>(acc, (float*)d_out);
}

// Round 9
// 357.082 us; speedup vs baseline: 1.6601x; 1.0327x over previous
//
#include <hip/hip_runtime.h>
#include <hip/hip_bf16.h>
#include <hip/hip_fp16.h>

#define N_BUS   2000
#define BATCH   512
#define NNODES  (BATCH * N_BUS)      // 1,024,000
#define NEDGES  3072000

constexpr float SN_INV     = 0.01f;                 // 1/SN_MVA
constexpr float ALPHA_C    = 0.9f;
constexpr float PHYS_SCALE = 0.02f;
constexpr float DEG2RAD_C  = 0.017453292519943295f;

typedef float v4f __attribute__((ext_vector_type(4)));   // nontemporal-load-compatible

// one-dword packed f16 atomic: (P,Q) in a single 32B-sector transaction.
// Measured wall: ~19.7e9 sector-tx/s chip-wide (R2/R3/R7 invariant) -> 3.07M tx = 156 us.
__device__ __forceinline__ void atomic_pk_add_h2(__half2* addr, float P, float Q) {
    __half2 v = __floats2half2_rn(P, Q);
#if __has_builtin(__builtin_amdgcn_global_atomic_fadd_v2f16)
    typedef _Float16 v2h __attribute__((ext_vector_type(2)));
    __builtin_amdgcn_global_atomic_fadd_v2f16(
        (__attribute__((address_space(1))) v2h*)(void*)addr,
        *reinterpret_cast<v2h*>(&v));
#else
    unsafeAtomicAdd(addr, v);
#endif
}

__device__ __forceinline__ float wave_reduce(float v) {
    #pragma unroll
    for (int off = 32; off > 0; off >>= 1) v += __shfl_down(v, off, 64);
    return v;
}

// ---------------- kernel 1: node prep (4 nodes/thread, all vector loads) ----------------
// ef[node] = half2(vm*cos, vm*sin); agg zeroed; acc[0] += sum((yp-yt)^2).
// mse uses (pr-tr)*y_std (y_mean cancels). 4 | N_BUS so i0..i0+3 never wraps.
__global__ __launch_bounds__(256) void node_prep(
    const float* __restrict__ y_pred, const float* __restrict__ y_true,
    const float* __restrict__ y_mean, const float* __restrict__ y_std,
    __half2* __restrict__ ef, __half2* __restrict__ agg, float* __restrict__ acc)
{
    int t = blockIdx.x * blockDim.x + threadIdx.x;
    int n0 = t * 4;
    int i0 = n0 % N_BUS;                       // multiple of 4 -> no wrap, aligned
    float4 pr0 = reinterpret_cast<const float4*>(y_pred + (size_t)n0*2)[0];
    float4 pr1 = reinterpret_cast<const float4*>(y_pred + (size_t)n0*2)[1];
    float4 tr0 = reinterpret_cast<const float4*>(y_true + (size_t)n0*2)[0];
    float4 tr1 = reinterpret_cast<const float4*>(y_true + (size_t)n0*2)[1];
    float4 ys0 = reinterpret_cast<const float4*>(y_std  + (size_t)i0*2)[0];
    float4 ys1 = reinterpret_cast<const float4*>(y_std  + (size_t)i0*2)[1];
    float4 ym0 = reinterpret_cast<const float4*>(y_mean + (size_t)i0*2)[0];
    float4 ym1 = reinterpret_cast<const float4*>(y_mean + (size_t)i0*2)[1];

    float d, msep = 0.0f;
    d = (pr0.x - tr0.x) * ys0.x; msep = fmaf(d, d, msep);
    d = (pr0.y - tr0.y) * ys0.y; msep = fmaf(d, d, msep);
    d = (pr0.z - tr0.z) * ys0.z; msep = fmaf(d, d, msep);
    d = (pr0.w - tr0.w) * ys0.w; msep = fmaf(d, d, msep);
    d = (pr1.x - tr1.x) * ys1.x; msep = fmaf(d, d, msep);
    d = (pr1.y - tr1.y) * ys1.y; msep = fmaf(d, d, msep);
    d = (pr1.z - tr1.z) * ys1.z; msep = fmaf(d, d, msep);
    d = (pr1.w - tr1.w) * ys1.w; msep = fmaf(d, d, msep);

    float vmA = fmaf(pr0.x, ys0.x, ym0.x), vaA = fmaf(pr0.y, ys0.y, ym0.y);
    float vmB = fmaf(pr0.z, ys0.z, ym0.z), vaB = fmaf(pr0.w, ys0.w, ym0.w);
    float vmC = fmaf(pr1.x, ys1.x, ym1.x), vaC = fmaf(pr1.y, ys1.y, ym1.y);
    float vmD = fmaf(pr1.z, ys1.z, ym1.z), vaD = fmaf(pr1.w, ys1.w, ym1.w);
    float s, c;
    __sincosf(vaA * DEG2RAD_C, &s, &c); __half2 eA = __floats2half2_rn(vmA*c, vmA*s);
    __sincosf(vaB * DEG2RAD_C, &s, &c); __half2 eB = __floats2half2_rn(vmB*c, vmB*s);
    __sincosf(vaC * DEG2RAD_C, &s, &c); __half2 eC = __floats2half2_rn(vmC*c, vmC*s);
    __sincosf(vaD * DEG2RAD_C, &s, &c); __half2 eD = __floats2half2_rn(vmD*c, vmD*s);
    *reinterpret_cast<uint4*>(ef + n0) = make_uint4(
        *reinterpret_cast<unsigned*>(&eA), *reinterpret_cast<unsigned*>(&eB),
        *reinterpret_cast<unsigned*>(&eC), *reinterpret_cast<unsigned*>(&eD));
    *reinterpret_cast<uint4*>(agg + n0) = make_uint4(0u, 0u, 0u, 0u);

    __shared__ float red[4];
    float v = wave_reduce(msep);
    int lane = threadIdx.x & 63, wid = threadIdx.x >> 6;
    if (lane == 0) red[wid] = v;
    __syncthreads();
    if (threadIdx.x == 0)
        unsafeAtomicAdd(acc + 0, red[0] + red[1] + red[2] + red[3]);
}

// ---------------- kernel 2: per-edge message + single-dword scatter-add ----------------
// AT THE ATOMIC WALL (see atomic_pk_add_h2 comment) — do not expect byte opts to move this.
__global__ __launch_bounds__(256) void edge_kernel(
    const int* __restrict__ eidx, const float* __restrict__ eattr,
    const float* __restrict__ e_mean, const float* __restrict__ e_std,
    const __half2* __restrict__ ef, __half2* __restrict__ agg)
{
    int e = blockIdx.x * blockDim.x + threadIdx.x;
    int s = __builtin_nontemporal_load(eidx + e);
    int d = __builtin_nontemporal_load(eidx + NEDGES + e);
    const v4f* eav = reinterpret_cast<const v4f*>(eattr) + e;
    v4f ea = __builtin_nontemporal_load(eav);
    float Gs = fmaf(ea.x, e_std[0], e_mean[0]);
    float Bs = fmaf(ea.y, e_std[1], e_mean[1]);
    float Gm = fmaf(ea.z, e_std[2], e_mean[2]);
    float Bm = fmaf(ea.w, e_std[3], e_mean[3]);
    float2 fi = __half22float2(ef[s]);   // (e_i, f_i)
    float2 fj = __half22float2(ef[d]);   // (e_j, f_j)
    float e_i = fi.x, f_i = fi.y;
    float e_j = fj.x, f_j = fj.y;
    float I_re = Gs*e_i - Bs*f_i + Gm*e_j - Bm*f_j;
    float I_im = Gs*f_i + Bs*e_i + Gm*f_j + Bm*e_j;
    float Pji = -(e_i*I_re + f_i*I_im);
    float Qji = -(f_i*I_re - e_i*I_im);
    atomic_pk_add_h2(agg + s, Pji, Qji);
}

// per-node imbalance term; vm^2 recomputed from half ef (rel err ~1e-3 on a ~0.01-weight term)
__device__ __forceinline__ void node_term(
    unsigned efb, unsigned agb, float shP, float shQ, int m, long n, int i,
    const float* __restrict__ x_input, const float* __restrict__ x_mean,
    const float* __restrict__ x_std, float& sqw, float& wsum)
{
    float2 efk = __half22float2(*reinterpret_cast<__half2*>(&efb));
    float2 agk = __half22float2(*reinterpret_cast<__half2*>(&agb));
    float vm2 = fmaf(efk.x, efk.x, efk.y * efk.y);
    float p = fmaf(x_input[n*7 + 0], x_std[i*7 + 0], x_mean[i*7 + 0]) * SN_INV;
    float q = fmaf(x_input[n*7 + 1], x_std[i*7 + 1], x_mean[i*7 + 1]) * SN_INV;
    float dP = fmaf(vm2, shP, p) - agk.x;
    float dQ = fmaf(-vm2, shQ, q) - agk.y;
    float w = m ? 1.0f : 0.0f;
    sqw = fmaf(dP*dP + dQ*dQ, w, sqw);
    wsum += w;
}

// ---------------- kernel 3: node finalize (4 nodes/thread) + last-block combine ----------------
__global__ __launch_bounds__(256) void node_final(
    const float* __restrict__ x_input,
    const float* __restrict__ x_mean, const float* __restrict__ x_std,
    const float* __restrict__ shunt, const int* __restrict__ mask,
    const __half2* __restrict__ ef, const __half2* __restrict__ agg,
    float* __restrict__ acc, float* __restrict__ out)
{
    int t = blockIdx.x * blockDim.x + threadIdx.x;
    int n0 = t * 4;
    int i0 = n0 % N_BUS;
    uint4 efu = *reinterpret_cast<const uint4*>(ef + n0);
    uint4 agu = *reinterpret_cast<const uint4*>(agg + n0);
    float4 sh0 = reinterpret_cast<const float4*>(shunt + (size_t)i0*2)[0];  // buses i0,i0+1
    float4 sh1 = reinterpret_cast<const float4*>(shunt + (size_t)i0*2)[1];  // buses i0+2,i0+3
    int4  mk  = *reinterpret_cast<const int4*>(mask + i0);

    float sqw = 0.0f, wsum = 0.0f;
    node_term(efu.x, agu.x, sh0.x, sh0.y, mk.x, (long)n0+0, i0+0, x_input, x_mean, x_std, sqw, wsum);
    node_term(efu.y, agu.y, sh0.z, sh0.w, mk.y, (long)n0+1, i0+1, x_input, x_mean, x_std, sqw, wsum);
    node_term(efu.z, agu.z, sh1.x, sh1.y, mk.z, (long)n0+2, i0+2, x_input, x_mean, x_std, sqw, wsum);
    node_term(efu.w, agu.w, sh1.z, sh1.w, mk.w, (long)n0+3, i0+3, x_input, x_mean, x_std, sqw, wsum);

    __shared__ float red0[4], red1[4];
    float v0 = wave_reduce(sqw);
    float v1 = wave_reduce(wsum);
    int lane = threadIdx.x & 63, wid = threadIdx.x >> 6;
    if (lane == 0) { red0[wid] = v0; red1[wid] = v1; }
    __syncthreads();
    if (threadIdx.x == 0) {
        unsafeAtomicAdd(acc + 1, red0[0] + red0[1] + red0[2] + red0[3]);
        unsafeAtomicAdd(acc + 2, red1[0] + red1[1] + red1[2] + red1[3]);
        __threadfence();
        unsigned prev = atomicAdd(reinterpret_cast<unsigned*>(acc + 3), 1u);
        if (prev == gridDim.x - 1) {
            // device-scope coherent reads via atomic RMW (cross-XCD safe)
            float mse = unsafeAtomicAdd(acc + 0, 0.0f) * (1.0f / (2.0f * NNODES));
            float sq  = unsafeAtomicAdd(acc + 1, 0.0f);
            float ww  = unsafeAtomicAdd(acc + 2, 0.0f);
            out[0] = ALPHA_C * mse + (1.0f - ALPHA_C) * PHYS_SCALE * (sq / ww);
        }
    }
}

extern "C" void kernel_launch(void* const* d_in, const int* in_sizes, int n_in,
                              void* d_out, int out_size, void* d_ws, size_t ws_size,
                              hipStream_t stream) {
    const float* y_pred    = (const float*)d_in[0];
    const float* y_true    = (const float*)d_in[1];
    const float* x_input   = (const float*)d_in[2];
    const int*   edge_idx  = (const int*)  d_in[3];
    const float* edge_attr = (const float*)d_in[4];
    const float* x_mean    = (const float*)d_in[5];
    const float* x_std     = (const float*)d_in[6];
    const float* y_mean    = (const float*)d_in[7];
    const float* y_std     = (const float*)d_in[8];
    const float* edge_mean = (const float*)d_in[9];
    const float* edge_std  = (const float*)d_in[10];
    const int*   load_mask = (const int*)  d_in[11];
    const float* shunt     = (const float*)d_in[12];

    // ws layout: agg half2[N] | ef half2[N] | acc float[4] (sums + completion counter)
    __half2* agg = (__half2*)d_ws;
    __half2* ef  = agg + NNODES;
    float*   acc = (float*)(ef + NNODES);

    (void)hipMemsetAsync(acc, 0, 16, stream);

    dim3 blk(256);
    node_prep<<<dim3(NNODES / 1024), blk, 0, stream>>>(
        y_pred, y_true, y_mean, y_std, ef, agg, acc);
    edge_kernel<<<dim3(NEDGES / 256), blk, 0, stream>>>(
        edge_idx, edge_attr, edge_mean, edge_std, ef, agg);
    node_final<<<dim3(NNODES / 1024), blk, 0, stream>>>(
        x_input, x_mean, x_std, shunt, load_mask, ef, agg, acc, (float*)d_out);
}